// Round 11
// baseline (177.796 us; speedup 1.0000x reference)
//
#include <hip/hip_runtime.h>

// NONA: out = softmax(-cdist(x, x_n), axis=1) @ y
//   x[4096,1024] f32, x_n[8192,1024] f32, y[8192,128] f32, log_T unused.
//
// R11: port the S-GEMM K-loop to the m201 8-phase template VERBATIM
// (the only schedule proven at 1563 TF on this chip; R5-R10's homemade
// schedules all plateau at 590-640 TF):
//  * tile 256x256, 8 waves = 2(wr: 128 rows) x 4(wc: 64 cols), Sacc[8][4].
//  * staging unit = half-tile [128 rows][64 K] = 16 KB = 2 global_load_lds
//    per thread. LDS: A-dbuf 2x32K @0, B-dbuf 2x32K @64K = 128 KiB.
//    dbuf index = K-tile parity (iter reads kt 2t in dbuf0 ph1-4, 2t+1 in
//    dbuf1 ph5-8; stages go to the NEXT same-parity K-tile's slots).
//  * 8 phases/iter; phase = {reads; stage; [vmcnt@ph4/8]; bar; lgkmcnt(0);
//    sched_barrier; setprio(1); 16 MFMA; setprio(0); bar; sched_barrier}.
//    Quadrant order per K-tile: (A0,B0),(A0,B1),(A1,B1),(A1,B0) -> af reused
//    ph1-2/ph3-4, 28 ds_read per K-tile per wave.
//  * stage schedule (seal -> stage one phase later; ledger):
//      ph1: Ah1(2t+1)+Bh0(2t+1)   [dbuf1; sealed prev ph7/ph8]
//      ph3: Ah0(2t+2)             [dbuf0 Ah0 sealed ph1]
//      ph4: Bh1(2t+2); vmcnt(4)   [B0h1 sealed ph2]
//      ph5: Ah1(2t+2)+Bh0(2t+2)   [sealed ph3/ph4]
//      ph7: Ah0(2t+3)             [dbuf1 Ah0 sealed ph5]
//      ph8: Bh1(2t+3); vmcnt(4)   [B1h1 sealed ph6]
//    RAW: ph4's vmcnt(4) leaves {ph3,ph4}=4 loads -> ph1's stages landed
//    (covers ph5-8 reads of kt 2t+1). ph8's vmcnt(4) leaves {ph7,ph8} ->
//    ph3/4/5 stages landed (covers next ph1-4 reads of kt 2t+2). Never 0
//    except last-iter ph4. Prologue: K0 full + K1{Ah0,Bh1} (12 loads),
//    vmcnt(4), barrier. Last iter (t=7): ph1 stage only, ph4 vmcnt(0).
//  * seam per bn (R8/R9-proven): sync; stage V halves (B region, 64K);
//    exp into Sacc; P-h0 (wc<2) -> A region [256][128] swz2; sync (drains V);
//    PV-h0; sync; P-h1; sync; PV-h1; sync. O[2][8]/wave (rows wave*32).
//  * grid 256 = 16 rb x 16 s (1 block/CU); block does bn=0,1 (two 256-col
//    tiles); Opart[16][N][C] 32 MB; lred+combine as before.
//
// ws: xb@0 8Mi | xnb@8Mi 16Mi | yT@24Mi 2Mi | xsq@26Mi 16Ki | xnsq +16Ki |
//     Lpart@26Mi+64Ki 256Ki | Opart@27Mi 32Mi  (59Mi; ws>=93Mi proven R5)

#define N_ 4096
#define M_ 8192
#define D_ 1024
#define C_ 128
#define SPLIT 16
#define NIT 8                 // iterations of 2 K-tiles (D/64/2)

typedef __bf16 bf16;
typedef __attribute__((ext_vector_type(8))) __bf16 bf16x8;
typedef __attribute__((ext_vector_type(4))) __bf16 bf16x4;
typedef __attribute__((ext_vector_type(4))) float f32x4;

__device__ __forceinline__ void async_copy16(const bf16* gp, void* lp) {
  __builtin_amdgcn_global_load_lds(
      (__attribute__((address_space(1))) void*)const_cast<bf16*>(gp),
      (__attribute__((address_space(3))) void*)lp, 16, 0, 0);
}

// 128-B-row tiles (A/B): 16B-granule XOR row&7 (0-conflict, R1-R10)
__device__ __forceinline__ int swz(int row, int gran) {
  return (row << 7) + ((gran ^ (row & 7)) << 4);
}
// 256-B-row tiles (P/V): 16 granules, XOR row&15
__device__ __forceinline__ int swz2(int row, int gran) {
  return (row << 8) + ((gran ^ (row & 15)) << 4);
}

// half-tile [128 rows][64 K] bf16 (16 KB): 2 loads/thread, src pre-swizzled
__device__ __forceinline__ void stageHalf(const bf16* src, char* lds, int tid) {
  const int lane = tid & 63, wave = tid >> 6;
#pragma unroll
  for (int j = 0; j < 2; ++j) {
    const int ch  = j * 8 + wave;
    const int off = ch * 1024 + lane * 16;
    const int row = off >> 7;
    const int gr  = ((off >> 4) & 7) ^ (row & 7);
    async_copy16(src + (size_t)row * D_ + gr * 8, lds + ch * 1024);
  }
}
// V half = yT[128 C][128 xn] (32 KB, 256-B rows): 4 loads/thread
__device__ __forceinline__ void stageV(const bf16* yT, int colbase, char* lds, int tid) {
  const int lane = tid & 63, wave = tid >> 6;
#pragma unroll
  for (int j = 0; j < 4; ++j) {
    const int ch  = j * 8 + wave;
    const int off = ch * 1024 + lane * 16;
    const int row = off >> 8;
    const int gr  = ((off >> 4) & 15) ^ (row & 15);
    async_copy16(yT + (size_t)row * M_ + colbase + gr * 8, lds + ch * 1024);
  }
}

#define VM4 asm volatile("s_waitcnt vmcnt(4)" ::: "memory")
#define VM0 asm volatile("s_waitcnt vmcnt(0)" ::: "memory")

// A-quadrant reads: af[i][ks] <- dbuf ABUF, wave's half-tile = wr, rows AH*64+
#define RD_A(AH, ABUF)                                                         \
  _Pragma("unroll") for (int ks = 0; ks < 2; ++ks)                             \
  _Pragma("unroll") for (int i = 0; i < 4; ++i)                                \
    af[i][ks] = *(const bf16x8*)((ABUF) + wr * 16384 +                         \
        swz((AH) * 64 + i * 16 + c, ks * 4 + g));
// B-quadrant reads: bv[j][ks] <- dbuf BBUF, half-tile wc>>1, cols BH*32+
#define RD_B(BH, BBUF)                                                         \
  _Pragma("unroll") for (int ks = 0; ks < 2; ++ks)                             \
  _Pragma("unroll") for (int j = 0; j < 2; ++j)                                \
    bv[j][ks] = *(const bf16x8*)((BBUF) + (wc >> 1) * 16384 +                  \
        swz((wc & 1) * 64 + (BH) * 32 + j * 16 + c, ks * 4 + g));
// barrier; wait ds; 16 MFMA cluster; barrier  (template phase tail)
#define MM(AH, BH)                                                             \
  __builtin_amdgcn_s_barrier();                                                \
  asm volatile("s_waitcnt lgkmcnt(0)" ::: "memory");                           \
  __builtin_amdgcn_sched_barrier(0);                                           \
  __builtin_amdgcn_s_setprio(1);                                               \
  _Pragma("unroll") for (int ks = 0; ks < 2; ++ks)                             \
  _Pragma("unroll") for (int j = 0; j < 2; ++j)                                \
  _Pragma("unroll") for (int i = 0; i < 4; ++i)                                \
    Sacc[(AH) * 4 + i][(BH) * 2 + j] = __builtin_amdgcn_mfma_f32_16x16x32_bf16(\
        bv[j][ks], af[i][ks], Sacc[(AH) * 4 + i][(BH) * 2 + j], 0, 0, 0);      \
  __builtin_amdgcn_s_setprio(0);                                               \
  __builtin_amdgcn_s_barrier();                                                \
  __builtin_amdgcn_sched_barrier(0);

__global__ __launch_bounds__(512, 1)
void nona_main(const bf16* __restrict__ xb, const bf16* __restrict__ xnb,
               const bf16* __restrict__ yT, const float* __restrict__ xsq,
               const float* __restrict__ xnsq, float* __restrict__ Opart,
               float* __restrict__ Lpart)
{
  __shared__ __align__(16) char Lds[131072];
  char* const A0 = Lds;             // dbuf0 A: h0@0, h1@16K   | tail: P [256][128]
  char* const A1 = Lds + 32768;     // dbuf1 A
  char* const B0 = Lds + 65536;     // dbuf0 B: h0@0, h1@16K   | tail: V-h0
  char* const B1 = Lds + 98304;     // dbuf1 B                 | tail: V-h1
  char* const Pb = Lds;             // P [256 x][128 xn], 256-B rows
  char* const V0 = Lds + 65536;     // V-h0 [128 C][128 xn]
  char* const V1 = Lds + 98304;     // V-h1

  const int tid  = threadIdx.x;
  const int lane = tid & 63;
  const int wave = tid >> 6;           // 8 waves: wr = wave>>2 (128 rows), wc = wave&3
  const int wr = wave >> 2, wc = wave & 3;
  const int g = lane >> 4, c = lane & 15;

  const int s    = blockIdx.x & 15;    // col group (512 cols); bid%8 -> XCD locality
  const int rb   = blockIdx.x >> 4;
  const int row0 = rb * 256;

  const bf16* xA = xb + (size_t)row0 * D_;

  f32x4 Oacc[2][8];
  const f32x4 zero = {0.f, 0.f, 0.f, 0.f};
#pragma unroll
  for (int rf = 0; rf < 2; ++rf)
#pragma unroll
    for (int cc = 0; cc < 8; ++cc) Oacc[rf][cc] = zero;
  float lsum[8] = {};

#pragma unroll 1
  for (int bn = 0; bn < 2; ++bn) {
    const int colbase = s * 512 + bn * 256;
    const bf16* xB = xnb + (size_t)colbase * D_;

    f32x4 Sacc[8][4];
#pragma unroll
    for (int rf = 0; rf < 8; ++rf)
#pragma unroll
      for (int cf = 0; cf < 4; ++cf) Sacc[rf][cf] = zero;

    // prologue: K0 full (4 half-tiles) + K1 {Ah0, Bh1} (12 loads/thread)
    stageHalf(xA, A0, tid);
    stageHalf(xA + 128 * D_, A0 + 16384, tid);
    stageHalf(xB, B0, tid);
    stageHalf(xB + 128 * D_, B0 + 16384, tid);
    stageHalf(xA + 64, A1, tid);
    stageHalf(xB + 64 + 128 * D_, B1 + 16384, tid);
    VM4;                               // K0 all landed (newest 4 = K1 pair)
    __builtin_amdgcn_s_barrier();
    __builtin_amdgcn_sched_barrier(0);

    bf16x8 af[4][2], bv[2][2];
#pragma unroll 1
    for (int t = 0; t < NIT; ++t) {
      const bool last = (t == NIT - 1);
      const bf16* a1 = xA + (2 * t + 1) * 64;   // K-tile 2t+1
      const bf16* b1 = xB + (2 * t + 1) * 64;
      const bf16* a2 = xA + (2 * t + 2) * 64;   // K-tile 2t+2 (dbuf0)
      const bf16* b2 = xB + (2 * t + 2) * 64;
      const bf16* a3 = xA + (2 * t + 3) * 64;   // K-tile 2t+3 (dbuf1)
      const bf16* b3 = xB + (2 * t + 3) * 64;

      // ph1: kt 2t quad (A0,B0); stage Ah1(2t+1), Bh0(2t+1)
      RD_A(0, A0) RD_B(0, B0)
      stageHalf(a1 + 128 * D_, A1 + 16384, tid);
      stageHalf(b1, B1, tid);
      MM(0, 0)
      // ph2: quad (A0,B1)
      RD_B(1, B0)
      MM(0, 1)
      // ph3: quad (A1,B1); stage Ah0(2t+2)
      RD_A(1, A0)
      if (!last) stageHalf(a2, A0, tid);
      MM(1, 1)
      // ph4: quad (A1,B0); stage Bh1(2t+2); vmcnt checkpoint
      RD_B(0, B0)
      if (!last) { stageHalf(b2 + 128 * D_, B0 + 16384, tid); VM4; }
      else VM0;
      MM(1, 0)
      // ph5: kt 2t+1 quad (A0,B0); stage Ah1(2t+2), Bh0(2t+2)
      RD_A(0, A1) RD_B(0, B1)
      if (!last) { stageHalf(a2 + 128 * D_, A0 + 16384, tid); stageHalf(b2, B0, tid); }
      MM(0, 0)
      // ph6: quad (A0,B1)
      RD_B(1, B1)
      MM(0, 1)
      // ph7: quad (A1,B1); stage Ah0(2t+3)
      RD_A(1, A1)
      if (!last) stageHalf(a3, A1, tid);
      MM(1, 1)
      // ph8: quad (A1,B0); stage Bh1(2t+3); vmcnt checkpoint
      RD_B(0, B1)
      if (!last) { stageHalf(b3 + 128 * D_, B1 + 16384, tid); VM4; }
      MM(1, 0)
    }
    __syncthreads();                   // seal K-loop readers; vm drained (iter7 ph4)

    stageV(yT, colbase, V0, tid);      // V halves -> B region (fly under exp)
    stageV(yT, colbase + 128, V1, tid);

    // exp: w = exp(-sqrt(max(xsq + xnsq - 2*dot, 0))); lane holds
    // S[xn = wc*64 + cf*16 + g*4 + r][xrow = wr*128 + rf*16 + c]
    {
      float xsr[8];
#pragma unroll
      for (int rf = 0; rf < 8; ++rf)
        xsr[rf] = xsq[row0 + wr * 128 + rf * 16 + c];
#pragma unroll
      for (int cf = 0; cf < 4; ++cf) {
        const float4 nsq4 = *(const float4*)(xnsq + colbase + wc * 64 + cf * 16 + g * 4);
#pragma unroll
        for (int rf = 0; rf < 8; ++rf)
#pragma unroll
          for (int r = 0; r < 4; ++r) {
            float d2 = xsr[rf] + ((const float*)&nsq4)[r] - 2.0f * Sacc[rf][cf][r];
            d2 = fmaxf(d2, 0.0f);
            const float wv = __expf(-sqrtf(d2));
            lsum[rf] += wv;
            Sacc[rf][cf][r] = wv;
          }
      }
    }

    // P-write (R8-proven layout): wave's strip -> its xn half of P [256][128]
#define WRITEP                                                                 \
    _Pragma("unroll") for (int rf = 0; rf < 8; ++rf)                           \
    _Pragma("unroll") for (int cf = 0; cf < 4; ++cf) {                         \
      bf16x4 pk;                                                               \
      _Pragma("unroll") for (int r = 0; r < 4; ++r) pk[r] = (bf16)Sacc[rf][cf][r]; \
      const int prow = wr * 128 + rf * 16 + c;                                 \
      const int gran = (wc & 1) * 8 + cf * 2 + (g >> 1);                       \
      *(bf16x4*)(Pb + (prow << 8) + ((gran ^ (prow & 15)) << 4) + (g & 1) * 8) = pk; \
    }

    if (wc < 2) { WRITEP }             // P-h0 = xn 0..127
    __syncthreads();                   // drains V (vmcnt0); P-h0 visible
#pragma unroll
    for (int ks = 0; ks < 4; ++ks) {   // PV half 0
      bf16x8 pa[2];
#pragma unroll
      for (int rf = 0; rf < 2; ++rf)
        pa[rf] = *(const bf16x8*)(Pb + swz2(wave * 32 + rf * 16 + c, ks * 4 + g));
      __builtin_amdgcn_s_setprio(1);
#pragma unroll
      for (int cc = 0; cc < 8; ++cc) {
        bf16x8 vb = *(const bf16x8*)(V0 + swz2(cc * 16 + c, ks * 4 + g));
#pragma unroll
        for (int rf = 0; rf < 2; ++rf)
          Oacc[rf][cc] = __builtin_amdgcn_mfma_f32_16x16x32_bf16(pa[rf], vb, Oacc[rf][cc], 0, 0, 0);
      }
      __builtin_amdgcn_s_setprio(0);
    }
    __syncthreads();                   // P-h0 readers done
    if (wc >= 2) { WRITEP }            // P-h1 = xn 128..255
    __syncthreads();                   // P-h1 visible
#pragma unroll
    for (int ks = 0; ks < 4; ++ks) {   // PV half 1
      bf16x8 pa[2];
#pragma unroll
      for (int rf = 0; rf < 2; ++rf)
        pa[rf] = *(const bf16x8*)(Pb + swz2(wave * 32 + rf * 16 + c, ks * 4 + g));
      __builtin_amdgcn_s_setprio(1);
#pragma unroll
      for (int cc = 0; cc < 8; ++cc) {
        bf16x8 vb = *(const bf16x8*)(V1 + swz2(cc * 16 + c, ks * 4 + g));
#pragma unroll
        for (int rf = 0; rf < 2; ++rf)
          Oacc[rf][cc] = __builtin_amdgcn_mfma_f32_16x16x32_bf16(pa[rf], vb, Oacc[rf][cc], 0, 0, 0);
      }
      __builtin_amdgcn_s_setprio(0);
    }
    __syncthreads();                   // seal P/V before next bn prologue
  }

  // ---- L reduce: over g (shfl), then the 4 wc waves (LDS) ----
  float* Lr = (float*)Lds;             // [4 wc][256 rows]
#pragma unroll
  for (int rf = 0; rf < 8; ++rf) {
    float v = lsum[rf];
    v += __shfl_xor(v, 16);
    v += __shfl_xor(v, 32);
    if (g == 0) Lr[wc * 256 + wr * 128 + rf * 16 + c] = v;
  }
  __syncthreads();
  if (tid < 256)
    Lpart[(size_t)s * N_ + row0 + tid] =
        Lr[tid] + Lr[256 + tid] + Lr[512 + tid] + Lr[768 + tid];

  float* ob = Opart + ((size_t)s * N_ + row0) * C_;
#pragma unroll
  for (int rf = 0; rf < 2; ++rf)
#pragma unroll
    for (int cc = 0; cc < 8; ++cc)
#pragma unroll
      for (int r = 0; r < 4; ++r)
        ob[(wave * 32 + rf * 16 + g * 4 + r) * C_ + cc * 16 + c] = Oacc[rf][cc][r];
}

// fused prep: rows [0,N) = x -> xb/xsq; rows [N, N+M) = xn -> xnb/xnsq
__global__ void prep_rows(const float* __restrict__ x, const float* __restrict__ xn,
                          bf16* __restrict__ xb, bf16* __restrict__ xnb,
                          float* __restrict__ xsq, float* __restrict__ xnsq)
{
  const int blk = blockIdx.x;
  const float* src; bf16* dst; float* sq; int row;
  if (blk < N_) { src = x;  dst = xb;  sq = xsq;  row = blk; }
  else          { src = xn; dst = xnb; sq = xnsq; row = blk - N_; }
  const int t = threadIdx.x;                   // 256 threads, 4 f32 each
  const float4 v = reinterpret_cast<const float4*>(src + (size_t)row * D_)[t];
  float ss = v.x * v.x + v.y * v.y + v.z * v.z + v.w * v.w;
  bf16x4 hv;
  hv[0] = (bf16)v.x; hv[1] = (bf16)v.y; hv[2] = (bf16)v.z; hv[3] = (bf16)v.w;
  *reinterpret_cast<bf16x4*>(dst + (size_t)row * D_ + t * 4) = hv;
#pragma unroll
  for (int o = 32; o > 0; o >>= 1) ss += __shfl_down(ss, o);
  __shared__ float red[4];
  if ((t & 63) == 0) red[t >> 6] = ss;
  __syncthreads();
  if (t == 0) sq[row] = red[0] + red[1] + red[2] + red[3];
}

// y[8192][128] f32 -> yT[128][8192] bf16
__global__ void prep_yT(const float* __restrict__ y, bf16* __restrict__ yT)
{
  __shared__ bf16 tile[C_][72];
  const int m0 = blockIdx.x * 64;
  const int t = threadIdx.x;
#pragma unroll
  for (int i = 0; i < 32; ++i) {
    const int idx = i * 256 + t;               // 0..8191
    const int ml = idx >> 7, cc = idx & 127;
    tile[cc][ml] = (bf16)y[(size_t)(m0 + ml) * C_ + cc];
  }
  __syncthreads();
#pragma unroll
  for (int i = 0; i < 32; ++i) {
    const int idx = i * 256 + t;
    const int cc = idx >> 6, ml = idx & 63;
    yT[(size_t)cc * M_ + m0 + ml] = tile[cc][ml];
  }
}

__global__ void combine(const float* __restrict__ Opart, const float* __restrict__ Lpart,
                        float* __restrict__ out)
{
  const int i = blockIdx.x * 256 + threadIdx.x;   // < N_*C_
  const int row = i >> 7;
  float o = 0.f, l = 0.f;
#pragma unroll
  for (int s = 0; s < SPLIT; ++s) {
    o += Opart[(size_t)s * N_ * C_ + i];
    l += Lpart[(size_t)s * N_ + row];
  }
  out[i] = o / l;
}

extern "C" void kernel_launch(void* const* d_in, const int* in_sizes, int n_in,
                              void* d_out, int out_size, void* d_ws, size_t ws_size,
                              hipStream_t stream)
{
  const float* x  = (const float*)d_in[0];
  const float* xn = (const float*)d_in[1];
  const float* y  = (const float*)d_in[2];
  // d_in[3] = log_T: computed-but-unused in the reference forward.
  float* out = (float*)d_out;

  char* ws = (char*)d_ws;
  bf16*  xb    = (bf16*)(ws);
  bf16*  xnb   = (bf16*)(ws + (size_t)8  * 1024 * 1024);
  bf16*  yT    = (bf16*)(ws + (size_t)24 * 1024 * 1024);
  float* xsq   = (float*)(ws + (size_t)26 * 1024 * 1024);
  float* xnsq  = (float*)(ws + (size_t)26 * 1024 * 1024 + 16 * 1024);
  float* Lpart = (float*)(ws + (size_t)26 * 1024 * 1024 + 64 * 1024);
  float* Opart = (float*)(ws + (size_t)27 * 1024 * 1024);   // 16 x 2 MiB

  prep_rows<<<N_ + M_, 256, 0, stream>>>(x, xn, xb, xnb, xsq, xnsq);
  prep_yT<<<M_ / 64, 256, 0, stream>>>(y, yT);
  nona_main<<<16 * SPLIT, 512, 0, stream>>>(xb, xnb, yT, xsq, xnsq, Opart, Lpart);
  combine<<<(N_ * C_) / 256, 256, 0, stream>>>(Opart, Lpart, out);
}

// Round 12
// 144.368 us; speedup vs baseline: 1.2315x; 1.2315x over previous
//
#include <hip/hip_runtime.h>

// NONA: out = softmax(-cdist(x, x_n), axis=1) @ y
//   x[4096,1024] f32, x_n[8192,1024] f32, y[8192,128] f32, log_T unused.
//
// R12 (R11 forensics: FETCH 151MB == predicted cross-XCD A-refetch; R5's
// 2270cy/step == its LDS+occupancy content (it was at ITS ceiling);
// 1-blk/CU big-tile rounds stall on lockstep barriers with no co-resident
// block to overlap (m114). Untested quadrant = R5 ledger + 2 blocks/CU +
// 8 waves + XCD-chunked mapping):
//  * BM=128 x BN=128, BK=64, 512 thr / 8 waves: wave tile 32x64
//    (Sacc[2][4], Oacc[2][4]); 12 ds_read + 16 MFMA per wave per K-step.
//  * LDS 64K: A dbuf 2x16K @0, B dbuf 2x16K @32K; seam aliases P[128][128]
//    ->A-region, V[128C][128]->B-region. __launch_bounds__(512,4) -> 2
//    blocks/CU (16 waves/CU): cross-block overlap fills barrier gaps.
//  * K-loop = R5's PROVEN ledger: step kk: stage(kk+1)->buf[(kk+1)&1]
//    (4 loads; WAR sealed by bar2 of kk-1); vmcnt(4) (own stage(kk) landed,
//    newest 4 = stage(kk+1)); s_barrier; sched_barrier; 12 ds_read + 16
//    MFMA (setprio); sched_barrier; s_barrier. Step 15: no stage, vmcnt(0).
//  * grid 512 = 32 rb x 16 s, 2D XCD chunk: xcd = (rb>>4)*4 + (s>>2)
//    (16 rb x 4 s per XCD -> 4MB A + 4MB B per-XCD set; A-panels no longer
//    pulled by all 8 XCDs). bid%8 == xcd by construction.
//  * seam per bn: sync; stageV (flies under exp); exp; writeP; sync
//    (drains V + publishes P); PV single pass (32 MFMA/wave); sync.
//
// ws: xb@0 8Mi | xnb@8Mi 16Mi | yT@24Mi 2Mi | xsq@26Mi 16Ki | xnsq +16Ki |
//     Lpart@26Mi+64Ki 256Ki | Opart@27Mi 32Mi  (59Mi; ws>=93Mi proven R5)

#define N_ 4096
#define M_ 8192
#define D_ 1024
#define C_ 128
#define SPLIT 16
#define MCOLS (M_ / SPLIT)    // 512
#define NBN (MCOLS / 128)     // 4
#define NKK (D_ / 64)         // 16

typedef __bf16 bf16;
typedef __attribute__((ext_vector_type(8))) __bf16 bf16x8;
typedef __attribute__((ext_vector_type(4))) __bf16 bf16x4;
typedef __attribute__((ext_vector_type(4))) float f32x4;

__device__ __forceinline__ void async_copy16(const bf16* gp, void* lp) {
  __builtin_amdgcn_global_load_lds(
      (__attribute__((address_space(1))) void*)const_cast<bf16*>(gp),
      (__attribute__((address_space(3))) void*)lp, 16, 0, 0);
}

// 128-B-row tiles (A/B): 16B-granule XOR row&7 (0-conflict, R1-R11)
__device__ __forceinline__ int swz(int row, int gran) {
  return (row << 7) + ((gran ^ (row & 7)) << 4);
}
// 256-B-row tiles (P/V): 16 granules, XOR row&15
__device__ __forceinline__ int swz2(int row, int gran) {
  return (row << 8) + ((gran ^ (row & 15)) << 4);
}

// [128][64]-bf16 tile (16K, 16 chunks): 2 loads/thread @512 thr, src pre-swz
__device__ __forceinline__ void stage16(const bf16* src, char* lds, int tid) {
  const int lane = tid & 63, wave = tid >> 6;
#pragma unroll
  for (int j = 0; j < 2; ++j) {
    const int ch  = j * 8 + wave;
    const int off = ch * 1024 + lane * 16;
    const int row = off >> 7;
    const int gr  = ((off >> 4) & 7) ^ (row & 7);
    async_copy16(src + (size_t)row * D_ + gr * 8, lds + ch * 1024);
  }
}
// V = yT[128 C][128 xn] (32K, 256-B rows): 4 loads/thread
__device__ __forceinline__ void stageV(const bf16* yT, int colbase, char* lds, int tid) {
  const int lane = tid & 63, wave = tid >> 6;
#pragma unroll
  for (int j = 0; j < 4; ++j) {
    const int ch  = j * 8 + wave;
    const int off = ch * 1024 + lane * 16;
    const int row = off >> 8;
    const int gr  = ((off >> 4) & 15) ^ (row & 15);
    async_copy16(yT + (size_t)row * M_ + colbase + gr * 8, lds + ch * 1024);
  }
}

#define VM4 asm volatile("s_waitcnt vmcnt(4)" ::: "memory")
#define VM0 asm volatile("s_waitcnt vmcnt(0)" ::: "memory")

__global__ __launch_bounds__(512, 4)   // 4 waves/EU => 2 blocks/CU
void nona_main(const bf16* __restrict__ xb, const bf16* __restrict__ xnb,
               const bf16* __restrict__ yT, const float* __restrict__ xsq,
               const float* __restrict__ xnsq, float* __restrict__ Opart,
               float* __restrict__ Lpart)
{
  __shared__ __align__(16) char Lds[65536];
  char* const A0 = Lds;             // x [128][64] even kk  | seam: P [128][128]
  char* const A1 = Lds + 16384;     // x [128][64] odd kk
  char* const B0 = Lds + 32768;     // xn [128][64] even kk | seam: V [128C][128]
  char* const B1 = Lds + 49152;     // xn [128][64] odd kk
  char* const Pb = A0;              // P, 256-B rows (swz2)
  char* const Vb = B0;              // V, 256-B rows (swz2)

  const int tid  = threadIdx.x;
  const int lane = tid & 63;
  const int wave = tid >> 6;           // 8 waves: wr = wave&3 (32 rows), wc = wave>>2
  const int wr = wave & 3, wc = wave >> 2;
  const int g = lane >> 4, c = lane & 15;

  // 2D XCD-chunked decode: xcd = bid&7 owns 16 rb x 4 s
  const int xcd = blockIdx.x & 7;
  const int idx = blockIdx.x >> 3;               // 0..63
  const int rb  = ((xcd >> 2) << 4) | (idx >> 2);   // 0..31
  const int s   = ((xcd & 3) << 2) | (idx & 3);     // 0..15
  const int row0 = rb * 128;
  const int col0 = s * MCOLS;

  const bf16* xA = xb + (size_t)row0 * D_;

  float xs[2];
#pragma unroll
  for (int rf = 0; rf < 2; ++rf)
    xs[rf] = xsq[row0 + wr * 32 + rf * 16 + c];

  f32x4 Oacc[2][4];
  const f32x4 zero = {0.f, 0.f, 0.f, 0.f};
#pragma unroll
  for (int rf = 0; rf < 2; ++rf)
#pragma unroll
    for (int cc = 0; cc < 4; ++cc) Oacc[rf][cc] = zero;
  float lsum[2] = {0.f, 0.f};

#pragma unroll 1
  for (int bn = 0; bn < NBN; ++bn) {
    const int colbase = col0 + bn * 128;
    const bf16* xB = xnb + (size_t)colbase * D_;

    f32x4 Sacc[2][4];
#pragma unroll
    for (int rf = 0; rf < 2; ++rf)
#pragma unroll
      for (int cf = 0; cf < 4; ++cf) Sacc[rf][cf] = zero;

    // prologue (prev bn sealed by post-PV syncthreads; vm=0): stage(0)
    stage16(xA, A0, tid);
    stage16(xB, B0, tid);

#pragma unroll 1
    for (int kk = 0; kk < NKK; ++kk) {
      if (kk < NKK - 1) {            // stage(kk+1); WAR sealed by bar2(kk-1)
        stage16(xA + (kk + 1) * 64, (kk & 1) ? A0 : A1, tid);
        stage16(xB + (kk + 1) * 64, (kk & 1) ? B0 : B1, tid);
        VM4;                         // own stage(kk) landed (newest 4 = kk+1)
      } else {
        VM0;                         // tail drain
      }
      __builtin_amdgcn_s_barrier();  // bar1: all waves' stage(kk) landed
      __builtin_amdgcn_sched_barrier(0);
      const char* Ac = (kk & 1) ? A1 : A0;
      const char* Bc = (kk & 1) ? B1 : B0;
      // swapped-S: Sacc = mfma(A=xn_frag, B=x_frag) -> lane holds
      // S[xn = wc*64+cf*16+g*4+r][xrow = wr*32+rf*16+c]
#pragma unroll
      for (int ks = 0; ks < 2; ++ks) {
        bf16x8 af[2], bv[4];
#pragma unroll
        for (int rf = 0; rf < 2; ++rf)
          af[rf] = *(const bf16x8*)(Ac + swz(wr * 32 + rf * 16 + c, ks * 4 + g));
#pragma unroll
        for (int j = 0; j < 4; ++j)
          bv[j] = *(const bf16x8*)(Bc + swz(wc * 64 + j * 16 + c, ks * 4 + g));
        __builtin_amdgcn_s_setprio(1);
#pragma unroll
        for (int j = 0; j < 4; ++j)
#pragma unroll
          for (int rf = 0; rf < 2; ++rf)
            Sacc[rf][j] = __builtin_amdgcn_mfma_f32_16x16x32_bf16(
                bv[j], af[rf], Sacc[rf][j], 0, 0, 0);
        __builtin_amdgcn_s_setprio(0);
      }
      __builtin_amdgcn_sched_barrier(0);
      __builtin_amdgcn_s_barrier();  // bar2: buf[kk&1] readers done (WAR seal)
    }
    __syncthreads();                 // seal kk15 readers; vm = 0

    stageV(yT, colbase, Vb, tid);    // V -> B region (flies under exp)

    // exp: w = exp(-sqrt(max(xsq + xnsq - 2*dot, 0))); accumulate l
#pragma unroll
    for (int cf = 0; cf < 4; ++cf) {
      const float4 nsq4 = *(const float4*)(xnsq + colbase + wc * 64 + cf * 16 + g * 4);
#pragma unroll
      for (int rf = 0; rf < 2; ++rf)
#pragma unroll
        for (int r = 0; r < 4; ++r) {
          float d2 = xs[rf] + ((const float*)&nsq4)[r] - 2.0f * Sacc[rf][cf][r];
          d2 = fmaxf(d2, 0.0f);
          const float wv = __expf(-sqrtf(d2));
          lsum[rf] += wv;
          Sacc[rf][cf][r] = wv;
        }
    }

    // P-write -> A region [128 xrow][128 xn] swz2 (b64 per (rf,cf))
#pragma unroll
    for (int rf = 0; rf < 2; ++rf)
#pragma unroll
      for (int cf = 0; cf < 4; ++cf) {
        bf16x4 pk;
#pragma unroll
        for (int r = 0; r < 4; ++r) pk[r] = (bf16)Sacc[rf][cf][r];
        const int prow = wr * 32 + rf * 16 + c;
        const int gran = wc * 8 + cf * 2 + (g >> 1);
        *(bf16x4*)(Pb + (prow << 8) + ((gran ^ (prow & 15)) << 4) + (g & 1) * 8) = pk;
      }
    __syncthreads();                 // drains V (vmcnt0); P visible

    // PV: O[32 rows x 64 C-half] += P[32 x 128] @ V^T  (V [128C][128])
#pragma unroll
    for (int ks = 0; ks < 4; ++ks) {
      bf16x8 pa[2];
#pragma unroll
      for (int rf = 0; rf < 2; ++rf)
        pa[rf] = *(const bf16x8*)(Pb + swz2(wr * 32 + rf * 16 + c, ks * 4 + g));
      __builtin_amdgcn_s_setprio(1);
#pragma unroll
      for (int cc = 0; cc < 4; ++cc) {
        bf16x8 vb = *(const bf16x8*)(Vb + swz2(wc * 64 + cc * 16 + c, ks * 4 + g));
#pragma unroll
        for (int rf = 0; rf < 2; ++rf)
          Oacc[rf][cc] = __builtin_amdgcn_mfma_f32_16x16x32_bf16(pa[rf], vb, Oacc[rf][cc], 0, 0, 0);
      }
      __builtin_amdgcn_s_setprio(0);
    }
    __syncthreads();                 // seal P/V readers before next bn prologue
  }

  // ---- L reduce: over g (shfl), then the wc pair (LDS) ----
  float* Lr = (float*)Lds;           // [2 wc][128 rows]
#pragma unroll
  for (int rf = 0; rf < 2; ++rf) {
    float v = lsum[rf];
    v += __shfl_xor(v, 16);
    v += __shfl_xor(v, 32);
    if (g == 0) Lr[wc * 128 + wr * 32 + rf * 16 + c] = v;
  }
  __syncthreads();
  if (tid < 128)
    Lpart[(size_t)s * N_ + row0 + tid] = Lr[tid] + Lr[128 + tid];

  float* ob = Opart + ((size_t)s * N_ + row0) * C_;
#pragma unroll
  for (int rf = 0; rf < 2; ++rf)
#pragma unroll
    for (int cc = 0; cc < 4; ++cc)
#pragma unroll
      for (int r = 0; r < 4; ++r)
        ob[(wr * 32 + rf * 16 + g * 4 + r) * C_ + wc * 64 + cc * 16 + c] = Oacc[rf][cc][r];
}

// fused prep: rows [0,N) = x -> xb/xsq; rows [N, N+M) = xn -> xnb/xnsq
__global__ void prep_rows(const float* __restrict__ x, const float* __restrict__ xn,
                          bf16* __restrict__ xb, bf16* __restrict__ xnb,
                          float* __restrict__ xsq, float* __restrict__ xnsq)
{
  const int blk = blockIdx.x;
  const float* src; bf16* dst; float* sq; int row;
  if (blk < N_) { src = x;  dst = xb;  sq = xsq;  row = blk; }
  else          { src = xn; dst = xnb; sq = xnsq; row = blk - N_; }
  const int t = threadIdx.x;                   // 256 threads, 4 f32 each
  const float4 v = reinterpret_cast<const float4*>(src + (size_t)row * D_)[t];
  float ss = v.x * v.x + v.y * v.y + v.z * v.z + v.w * v.w;
  bf16x4 hv;
  hv[0] = (bf16)v.x; hv[1] = (bf16)v.y; hv[2] = (bf16)v.z; hv[3] = (bf16)v.w;
  *reinterpret_cast<bf16x4*>(dst + (size_t)row * D_ + t * 4) = hv;
#pragma unroll
  for (int o = 32; o > 0; o >>= 1) ss += __shfl_down(ss, o);
  __shared__ float red[4];
  if ((t & 63) == 0) red[t >> 6] = ss;
  __syncthreads();
  if (t == 0) sq[row] = red[0] + red[1] + red[2] + red[3];
}

// y[8192][128] f32 -> yT[128][8192] bf16
__global__ void prep_yT(const float* __restrict__ y, bf16* __restrict__ yT)
{
  __shared__ bf16 tile[C_][72];
  const int m0 = blockIdx.x * 64;
  const int t = threadIdx.x;
#pragma unroll
  for (int i = 0; i < 32; ++i) {
    const int idx = i * 256 + t;               // 0..8191
    const int ml = idx >> 7, cc = idx & 127;
    tile[cc][ml] = (bf16)y[(size_t)(m0 + ml) * C_ + cc];
  }
  __syncthreads();
#pragma unroll
  for (int i = 0; i < 32; ++i) {
    const int idx = i * 256 + t;
    const int cc = idx >> 6, ml = idx & 63;
    yT[(size_t)cc * M_ + m0 + ml] = tile[cc][ml];
  }
}

__global__ void combine(const float* __restrict__ Opart, const float* __restrict__ Lpart,
                        float* __restrict__ out)
{
  const int i = blockIdx.x * 256 + threadIdx.x;   // < N_*C_
  const int row = i >> 7;
  float o = 0.f, l = 0.f;
#pragma unroll
  for (int s = 0; s < SPLIT; ++s) {
    o += Opart[(size_t)s * N_ * C_ + i];
    l += Lpart[(size_t)s * N_ + row];
  }
  out[i] = o / l;
}

extern "C" void kernel_launch(void* const* d_in, const int* in_sizes, int n_in,
                              void* d_out, int out_size, void* d_ws, size_t ws_size,
                              hipStream_t stream)
{
  const float* x  = (const float*)d_in[0];
  const float* xn = (const float*)d_in[1];
  const float* y  = (const float*)d_in[2];
  // d_in[3] = log_T: computed-but-unused in the reference forward.
  float* out = (float*)d_out;

  char* ws = (char*)d_ws;
  bf16*  xb    = (bf16*)(ws);
  bf16*  xnb   = (bf16*)(ws + (size_t)8  * 1024 * 1024);
  bf16*  yT    = (bf16*)(ws + (size_t)24 * 1024 * 1024);
  float* xsq   = (float*)(ws + (size_t)26 * 1024 * 1024);
  float* xnsq  = (float*)(ws + (size_t)26 * 1024 * 1024 + 16 * 1024);
  float* Lpart = (float*)(ws + (size_t)26 * 1024 * 1024 + 64 * 1024);
  float* Opart = (float*)(ws + (size_t)27 * 1024 * 1024);   // 16 x 2 MiB

  prep_rows<<<N_ + M_, 256, 0, stream>>>(x, xn, xb, xnb, xsq, xnsq);
  prep_yT<<<M_ / 64, 256, 0, stream>>>(y, yT);
  nona_main<<<32 * SPLIT, 512, 0, stream>>>(xb, xnb, yT, xsq, xnsq, Opart, Lpart);
  combine<<<(N_ * C_) / 256, 256, 0, stream>>>(Opart, Lpart, out);
}

// Round 13
// 123.521 us; speedup vs baseline: 1.4394x; 1.1688x over previous
//
#include <hip/hip_runtime.h>

// NONA: out = softmax(-cdist(x, x_n), axis=1) @ y
//   x[4096,1024] f32, x_n[8192,1024] f32, y[8192,128] f32, log_T unused.
//
// R13 (R12 model closed: 32x64 wave tile = 0.75 ds_read/MFMA -> LDS-port
// ceiling 45% MfmaUtil; R5/R12 both sit at ~62% of it. The remaining lever
// is fragment-reuse geometry, not scheduling):
//  * same 128x128 block tile + R12 ledger + seam, but 4 waves (256 thr),
//    each owning a 64x64 quadrant (wr=wave>>1, wc=wave&1): Sacc[4][4],
//    Oacc[4][4]; per K-step 16 ds_read feed 32 MFMA = 0.5 r/M (ceiling 67%).
//    PV likewise 32 reads / 64 MFMA.
//  * LDS 64K unchanged -> 2 blocks/CU (8 waves/CU, R12-proven overlap);
//    VGPR ~180 -> __launch_bounds__(256,2).
//  * staging: 8 loads/thread/step (A 4 + B 4) -> vmcnt(8); stageV 8 loads.
//  * grid 512 = 32 rb x 16 s = exactly 2/CU; 2D XCD chunk as R12.
//
// ws: xb@0 8Mi | xnb@8Mi 16Mi | yT@24Mi 2Mi | xsq@26Mi 16Ki | xnsq +16Ki |
//     Lpart@26Mi+64Ki 256Ki | Opart@27Mi 32Mi  (59Mi; ws>=93Mi proven R5)

#define N_ 4096
#define M_ 8192
#define D_ 1024
#define C_ 128
#define SPLIT 16
#define MCOLS (M_ / SPLIT)    // 512
#define NBN (MCOLS / 128)     // 4
#define NKK (D_ / 64)         // 16

typedef __bf16 bf16;
typedef __attribute__((ext_vector_type(8))) __bf16 bf16x8;
typedef __attribute__((ext_vector_type(4))) __bf16 bf16x4;
typedef __attribute__((ext_vector_type(4))) float f32x4;

__device__ __forceinline__ void async_copy16(const bf16* gp, void* lp) {
  __builtin_amdgcn_global_load_lds(
      (__attribute__((address_space(1))) void*)const_cast<bf16*>(gp),
      (__attribute__((address_space(3))) void*)lp, 16, 0, 0);
}

// 128-B-row tiles (A/B): 16B-granule XOR row&7 (0-conflict, R1-R12)
__device__ __forceinline__ int swz(int row, int gran) {
  return (row << 7) + ((gran ^ (row & 7)) << 4);
}
// 256-B-row tiles (P/V): 16 granules, XOR row&15
__device__ __forceinline__ int swz2(int row, int gran) {
  return (row << 8) + ((gran ^ (row & 15)) << 4);
}

// [128][64]-bf16 tile (16K, 16 chunks): 4 loads/thread @256 thr, src pre-swz
__device__ __forceinline__ void stage16(const bf16* src, char* lds, int tid) {
  const int lane = tid & 63, wave = tid >> 6;
#pragma unroll
  for (int j = 0; j < 4; ++j) {
    const int ch  = j * 4 + wave;
    const int off = ch * 1024 + lane * 16;
    const int row = off >> 7;
    const int gr  = ((off >> 4) & 7) ^ (row & 7);
    async_copy16(src + (size_t)row * D_ + gr * 8, lds + ch * 1024);
  }
}
// V = yT[128 C][128 xn] (32K, 256-B rows): 8 loads/thread @256 thr
__device__ __forceinline__ void stageV(const bf16* yT, int colbase, char* lds, int tid) {
  const int lane = tid & 63, wave = tid >> 6;
#pragma unroll
  for (int j = 0; j < 8; ++j) {
    const int ch  = j * 4 + wave;
    const int off = ch * 1024 + lane * 16;
    const int row = off >> 8;
    const int gr  = ((off >> 4) & 15) ^ (row & 15);
    async_copy16(yT + (size_t)row * M_ + colbase + gr * 8, lds + ch * 1024);
  }
}

#define VM8 asm volatile("s_waitcnt vmcnt(8)" ::: "memory")
#define VM0 asm volatile("s_waitcnt vmcnt(0)" ::: "memory")

__global__ __launch_bounds__(256, 2)   // 2 waves/EU => 2 blocks/CU
void nona_main(const bf16* __restrict__ xb, const bf16* __restrict__ xnb,
               const bf16* __restrict__ yT, const float* __restrict__ xsq,
               const float* __restrict__ xnsq, float* __restrict__ Opart,
               float* __restrict__ Lpart)
{
  __shared__ __align__(16) char Lds[65536];
  char* const A0 = Lds;             // x [128][64] even kk  | seam: P [128][128]
  char* const A1 = Lds + 16384;     // x [128][64] odd kk
  char* const B0 = Lds + 32768;     // xn [128][64] even kk | seam: V [128C][128]
  char* const B1 = Lds + 49152;     // xn [128][64] odd kk
  char* const Pb = A0;              // P, 256-B rows (swz2)
  char* const Vb = B0;              // V, 256-B rows (swz2)

  const int tid  = threadIdx.x;
  const int lane = tid & 63;
  const int wave = tid >> 6;           // 4 waves: wr = wave>>1 (64 rows), wc = wave&1
  const int wr = wave >> 1, wc = wave & 1;
  const int g = lane >> 4, c = lane & 15;

  // 2D XCD-chunked decode: xcd = bid&7 owns 16 rb x 4 s
  const int xcd = blockIdx.x & 7;
  const int idx = blockIdx.x >> 3;               // 0..63
  const int rb  = ((xcd >> 2) << 4) | (idx >> 2);   // 0..31
  const int s   = ((xcd & 3) << 2) | (idx & 3);     // 0..15
  const int row0 = rb * 128;
  const int col0 = s * MCOLS;

  const bf16* xA = xb + (size_t)row0 * D_;

  float xs[4];
#pragma unroll
  for (int rf = 0; rf < 4; ++rf)
    xs[rf] = xsq[row0 + wr * 64 + rf * 16 + c];

  f32x4 Oacc[4][4];
  const f32x4 zero = {0.f, 0.f, 0.f, 0.f};
#pragma unroll
  for (int rf = 0; rf < 4; ++rf)
#pragma unroll
    for (int cc = 0; cc < 4; ++cc) Oacc[rf][cc] = zero;
  float lsum[4] = {0.f, 0.f, 0.f, 0.f};

#pragma unroll 1
  for (int bn = 0; bn < NBN; ++bn) {
    const int colbase = col0 + bn * 128;
    const bf16* xB = xnb + (size_t)colbase * D_;

    f32x4 Sacc[4][4];
#pragma unroll
    for (int rf = 0; rf < 4; ++rf)
#pragma unroll
      for (int cf = 0; cf < 4; ++cf) Sacc[rf][cf] = zero;

    // prologue (prev bn sealed by post-PV syncthreads; vm=0): stage(0)
    stage16(xA, A0, tid);
    stage16(xB, B0, tid);

#pragma unroll 1
    for (int kk = 0; kk < NKK; ++kk) {
      if (kk < NKK - 1) {            // stage(kk+1); WAR sealed by bar2(kk-1)
        stage16(xA + (kk + 1) * 64, (kk & 1) ? A0 : A1, tid);
        stage16(xB + (kk + 1) * 64, (kk & 1) ? B0 : B1, tid);
        VM8;                         // own stage(kk) landed (newest 8 = kk+1)
      } else {
        VM0;                         // tail drain
      }
      __builtin_amdgcn_s_barrier();  // bar1: all waves' stage(kk) landed
      __builtin_amdgcn_sched_barrier(0);
      const char* Ac = (kk & 1) ? A1 : A0;
      const char* Bc = (kk & 1) ? B1 : B0;
      // swapped-S: Sacc = mfma(A=xn_frag, B=x_frag) -> lane holds
      // S[xn = wc*64+cf*16+g*4+r][xrow = wr*64+rf*16+c]
#pragma unroll
      for (int ks = 0; ks < 2; ++ks) {
        bf16x8 af[4], bv[4];
#pragma unroll
        for (int rf = 0; rf < 4; ++rf)
          af[rf] = *(const bf16x8*)(Ac + swz(wr * 64 + rf * 16 + c, ks * 4 + g));
#pragma unroll
        for (int j = 0; j < 4; ++j)
          bv[j] = *(const bf16x8*)(Bc + swz(wc * 64 + j * 16 + c, ks * 4 + g));
        __builtin_amdgcn_s_setprio(1);
#pragma unroll
        for (int j = 0; j < 4; ++j)
#pragma unroll
          for (int rf = 0; rf < 4; ++rf)
            Sacc[rf][j] = __builtin_amdgcn_mfma_f32_16x16x32_bf16(
                bv[j], af[rf], Sacc[rf][j], 0, 0, 0);
        __builtin_amdgcn_s_setprio(0);
      }
      __builtin_amdgcn_sched_barrier(0);
      __builtin_amdgcn_s_barrier();  // bar2: buf[kk&1] readers done (WAR seal)
    }
    __syncthreads();                 // seal kk15 readers; vm = 0

    stageV(yT, colbase, Vb, tid);    // V -> B region (flies under exp)

    // exp: w = exp(-sqrt(max(xsq + xnsq - 2*dot, 0))); accumulate l
#pragma unroll
    for (int cf = 0; cf < 4; ++cf) {
      const float4 nsq4 = *(const float4*)(xnsq + colbase + wc * 64 + cf * 16 + g * 4);
#pragma unroll
      for (int rf = 0; rf < 4; ++rf)
#pragma unroll
        for (int r = 0; r < 4; ++r) {
          float d2 = xs[rf] + ((const float*)&nsq4)[r] - 2.0f * Sacc[rf][cf][r];
          d2 = fmaxf(d2, 0.0f);
          const float wv = __expf(-sqrtf(d2));
          lsum[rf] += wv;
          Sacc[rf][cf][r] = wv;
        }
    }

    // P-write -> A region [128 xrow][128 xn] swz2 (b64 per (rf,cf))
#pragma unroll
    for (int rf = 0; rf < 4; ++rf)
#pragma unroll
      for (int cf = 0; cf < 4; ++cf) {
        bf16x4 pk;
#pragma unroll
        for (int r = 0; r < 4; ++r) pk[r] = (bf16)Sacc[rf][cf][r];
        const int prow = wr * 64 + rf * 16 + c;
        const int gran = wc * 8 + cf * 2 + (g >> 1);
        *(bf16x4*)(Pb + (prow << 8) + ((gran ^ (prow & 15)) << 4) + (g & 1) * 8) = pk;
      }
    __syncthreads();                 // drains V (vmcnt0); P visible

    // PV: O[64 rows x 64 C-half] += P[64 x 128] @ V^T  (V [128C][128])
#pragma unroll
    for (int ks = 0; ks < 4; ++ks) {
      bf16x8 pa[4], vb[4];
#pragma unroll
      for (int rf = 0; rf < 4; ++rf)
        pa[rf] = *(const bf16x8*)(Pb + swz2(wr * 64 + rf * 16 + c, ks * 4 + g));
#pragma unroll
      for (int cc = 0; cc < 4; ++cc)
        vb[cc] = *(const bf16x8*)(Vb + swz2(wc * 64 + cc * 16 + c, ks * 4 + g));
      __builtin_amdgcn_s_setprio(1);
#pragma unroll
      for (int cc = 0; cc < 4; ++cc)
#pragma unroll
        for (int rf = 0; rf < 4; ++rf)
          Oacc[rf][cc] = __builtin_amdgcn_mfma_f32_16x16x32_bf16(pa[rf], vb[cc], Oacc[rf][cc], 0, 0, 0);
      __builtin_amdgcn_s_setprio(0);
    }
    __syncthreads();                 // seal P/V readers before next bn prologue
  }

  // ---- L reduce: over g (shfl), then the wc pair (LDS) ----
  float* Lr = (float*)Lds;           // [2 wc][128 rows]
#pragma unroll
  for (int rf = 0; rf < 4; ++rf) {
    float v = lsum[rf];
    v += __shfl_xor(v, 16);
    v += __shfl_xor(v, 32);
    if (g == 0) Lr[wc * 128 + wr * 64 + rf * 16 + c] = v;
  }
  __syncthreads();
  if (tid < 128)
    Lpart[(size_t)s * N_ + row0 + tid] = Lr[tid] + Lr[128 + tid];

  float* ob = Opart + ((size_t)s * N_ + row0) * C_;
#pragma unroll
  for (int rf = 0; rf < 4; ++rf)
#pragma unroll
    for (int cc = 0; cc < 4; ++cc)
#pragma unroll
      for (int r = 0; r < 4; ++r)
        ob[(wr * 64 + rf * 16 + g * 4 + r) * C_ + wc * 64 + cc * 16 + c] = Oacc[rf][cc][r];
}

// fused prep: rows [0,N) = x -> xb/xsq; rows [N, N+M) = xn -> xnb/xnsq
__global__ void prep_rows(const float* __restrict__ x, const float* __restrict__ xn,
                          bf16* __restrict__ xb, bf16* __restrict__ xnb,
                          float* __restrict__ xsq, float* __restrict__ xnsq)
{
  const int blk = blockIdx.x;
  const float* src; bf16* dst; float* sq; int row;
  if (blk < N_) { src = x;  dst = xb;  sq = xsq;  row = blk; }
  else          { src = xn; dst = xnb; sq = xnsq; row = blk - N_; }
  const int t = threadIdx.x;                   // 256 threads, 4 f32 each
  const float4 v = reinterpret_cast<const float4*>(src + (size_t)row * D_)[t];
  float ss = v.x * v.x + v.y * v.y + v.z * v.z + v.w * v.w;
  bf16x4 hv;
  hv[0] = (bf16)v.x; hv[1] = (bf16)v.y; hv[2] = (bf16)v.z; hv[3] = (bf16)v.w;
  *reinterpret_cast<bf16x4*>(dst + (size_t)row * D_ + t * 4) = hv;
#pragma unroll
  for (int o = 32; o > 0; o >>= 1) ss += __shfl_down(ss, o);
  __shared__ float red[4];
  if ((t & 63) == 0) red[t >> 6] = ss;
  __syncthreads();
  if (t == 0) sq[row] = red[0] + red[1] + red[2] + red[3];
}

// y[8192][128] f32 -> yT[128][8192] bf16
__global__ void prep_yT(const float* __restrict__ y, bf16* __restrict__ yT)
{
  __shared__ bf16 tile[C_][72];
  const int m0 = blockIdx.x * 64;
  const int t = threadIdx.x;
#pragma unroll
  for (int i = 0; i < 32; ++i) {
    const int idx = i * 256 + t;               // 0..8191
    const int ml = idx >> 7, cc = idx & 127;
    tile[cc][ml] = (bf16)y[(size_t)(m0 + ml) * C_ + cc];
  }
  __syncthreads();
#pragma unroll
  for (int i = 0; i < 32; ++i) {
    const int idx = i * 256 + t;
    const int cc = idx >> 6, ml = idx & 63;
    yT[(size_t)cc * M_ + m0 + ml] = tile[cc][ml];
  }
}

__global__ void combine(const float* __restrict__ Opart, const float* __restrict__ Lpart,
                        float* __restrict__ out)
{
  const int i = blockIdx.x * 256 + threadIdx.x;   // < N_*C_
  const int row = i >> 7;
  float o = 0.f, l = 0.f;
#pragma unroll
  for (int s = 0; s < SPLIT; ++s) {
    o += Opart[(size_t)s * N_ * C_ + i];
    l += Lpart[(size_t)s * N_ + row];
  }
  out[i] = o / l;
}

extern "C" void kernel_launch(void* const* d_in, const int* in_sizes, int n_in,
                              void* d_out, int out_size, void* d_ws, size_t ws_size,
                              hipStream_t stream)
{
  const float* x  = (const float*)d_in[0];
  const float* xn = (const float*)d_in[1];
  const float* y  = (const float*)d_in[2];
  // d_in[3] = log_T: computed-but-unused in the reference forward.
  float* out = (float*)d_out;

  char* ws = (char*)d_ws;
  bf16*  xb    = (bf16*)(ws);
  bf16*  xnb   = (bf16*)(ws + (size_t)8  * 1024 * 1024);
  bf16*  yT    = (bf16*)(ws + (size_t)24 * 1024 * 1024);
  float* xsq   = (float*)(ws + (size_t)26 * 1024 * 1024);
  float* xnsq  = (float*)(ws + (size_t)26 * 1024 * 1024 + 16 * 1024);
  float* Lpart = (float*)(ws + (size_t)26 * 1024 * 1024 + 64 * 1024);
  float* Opart = (float*)(ws + (size_t)27 * 1024 * 1024);   // 16 x 2 MiB

  prep_rows<<<N_ + M_, 256, 0, stream>>>(x, xn, xb, xnb, xsq, xnsq);
  prep_yT<<<M_ / 64, 256, 0, stream>>>(y, yT);
  nona_main<<<32 * SPLIT, 256, 0, stream>>>(xb, xnb, yT, xsq, xnsq, Opart, Lpart);
  combine<<<(N_ * C_) / 256, 256, 0, stream>>>(Opart, Lpart, out);
}

// Round 14
// 122.220 us; speedup vs baseline: 1.4547x; 1.0106x over previous
//
#include <hip/hip_runtime.h>

// NONA: out = softmax(-cdist(x, x_n), axis=1) @ y
//   x[4096,1024] f32, x_n[8192,1024] f32, y[8192,128] f32, log_T unused.
//
// R14 (R13 model: wall 3000 cy/step vs 1536 LDS + 1024 MFMA content; the
// ~1400 residual is 2x s_barrier lockstep. Single change: DELETE bar2):
//  * WAR proof: wave's reads(kk-1) are consumed by its MFMA(kk-1) (lgkmcnt)
//    BEFORE it reaches bar1(kk); so bar1(kk) passed by all waves ==> all
//    reads of buf[(kk+1)&1] complete ==> stage(kk+1) issued AFTER bar1(kk)
//    is WAR-safe. bar2 deleted.
//  * step kk: vmcnt(0) [outstanding == own stage(kk): stage(kk+1) not yet
//    issued]; s_barrier; sched_barrier; reads(ks0); stage(kk+1); MFMA(ks0);
//    reads(ks1); MFMA(ks1). Stage flight unchanged (one compute phase).
//  * all else frozen from R13: 128x128 tile, 4 waves x 64x64 (0.5 r/M),
//    LDS 64K -> 2 blocks/CU, seam (V under exp, P/V alias A/B), 2D XCD
//    chunking, SPLIT=16, grid 512.
//
// ws: xb@0 8Mi | xnb@8Mi 16Mi | yT@24Mi 2Mi | xsq@26Mi 16Ki | xnsq +16Ki |
//     Lpart@26Mi+64Ki 256Ki | Opart@27Mi 32Mi  (59Mi; ws>=93Mi proven R5)

#define N_ 4096
#define M_ 8192
#define D_ 1024
#define C_ 128
#define SPLIT 16
#define MCOLS (M_ / SPLIT)    // 512
#define NBN (MCOLS / 128)     // 4
#define NKK (D_ / 64)         // 16

typedef __bf16 bf16;
typedef __attribute__((ext_vector_type(8))) __bf16 bf16x8;
typedef __attribute__((ext_vector_type(4))) __bf16 bf16x4;
typedef __attribute__((ext_vector_type(4))) float f32x4;

__device__ __forceinline__ void async_copy16(const bf16* gp, void* lp) {
  __builtin_amdgcn_global_load_lds(
      (__attribute__((address_space(1))) void*)const_cast<bf16*>(gp),
      (__attribute__((address_space(3))) void*)lp, 16, 0, 0);
}

// 128-B-row tiles (A/B): 16B-granule XOR row&7 (0-conflict, R1-R13)
__device__ __forceinline__ int swz(int row, int gran) {
  return (row << 7) + ((gran ^ (row & 7)) << 4);
}
// 256-B-row tiles (P/V): 16 granules, XOR row&15
__device__ __forceinline__ int swz2(int row, int gran) {
  return (row << 8) + ((gran ^ (row & 15)) << 4);
}

// [128][64]-bf16 tile (16K, 16 chunks): 4 loads/thread @256 thr, src pre-swz
__device__ __forceinline__ void stage16(const bf16* src, char* lds, int tid) {
  const int lane = tid & 63, wave = tid >> 6;
#pragma unroll
  for (int j = 0; j < 4; ++j) {
    const int ch  = j * 4 + wave;
    const int off = ch * 1024 + lane * 16;
    const int row = off >> 7;
    const int gr  = ((off >> 4) & 7) ^ (row & 7);
    async_copy16(src + (size_t)row * D_ + gr * 8, lds + ch * 1024);
  }
}
// V = yT[128 C][128 xn] (32K, 256-B rows): 8 loads/thread @256 thr
__device__ __forceinline__ void stageV(const bf16* yT, int colbase, char* lds, int tid) {
  const int lane = tid & 63, wave = tid >> 6;
#pragma unroll
  for (int j = 0; j < 8; ++j) {
    const int ch  = j * 4 + wave;
    const int off = ch * 1024 + lane * 16;
    const int row = off >> 8;
    const int gr  = ((off >> 4) & 15) ^ (row & 15);
    async_copy16(yT + (size_t)row * M_ + colbase + gr * 8, lds + ch * 1024);
  }
}

#define VM0 asm volatile("s_waitcnt vmcnt(0)" ::: "memory")

__global__ __launch_bounds__(256, 2)   // 2 waves/EU => 2 blocks/CU
void nona_main(const bf16* __restrict__ xb, const bf16* __restrict__ xnb,
               const bf16* __restrict__ yT, const float* __restrict__ xsq,
               const float* __restrict__ xnsq, float* __restrict__ Opart,
               float* __restrict__ Lpart)
{
  __shared__ __align__(16) char Lds[65536];
  char* const A0 = Lds;             // x [128][64] even kk  | seam: P [128][128]
  char* const A1 = Lds + 16384;     // x [128][64] odd kk
  char* const B0 = Lds + 32768;     // xn [128][64] even kk | seam: V [128C][128]
  char* const B1 = Lds + 49152;     // xn [128][64] odd kk
  char* const Pb = A0;              // P, 256-B rows (swz2)
  char* const Vb = B0;              // V, 256-B rows (swz2)

  const int tid  = threadIdx.x;
  const int lane = tid & 63;
  const int wave = tid >> 6;           // 4 waves: wr = wave>>1 (64 rows), wc = wave&1
  const int wr = wave >> 1, wc = wave & 1;
  const int g = lane >> 4, c = lane & 15;

  // 2D XCD-chunked decode: xcd = bid&7 owns 16 rb x 4 s
  const int xcd = blockIdx.x & 7;
  const int idx = blockIdx.x >> 3;               // 0..63
  const int rb  = ((xcd >> 2) << 4) | (idx >> 2);   // 0..31
  const int s   = ((xcd & 3) << 2) | (idx & 3);     // 0..15
  const int row0 = rb * 128;
  const int col0 = s * MCOLS;

  const bf16* xA = xb + (size_t)row0 * D_;

  float xs[4];
#pragma unroll
  for (int rf = 0; rf < 4; ++rf)
    xs[rf] = xsq[row0 + wr * 64 + rf * 16 + c];

  f32x4 Oacc[4][4];
  const f32x4 zero = {0.f, 0.f, 0.f, 0.f};
#pragma unroll
  for (int rf = 0; rf < 4; ++rf)
#pragma unroll
    for (int cc = 0; cc < 4; ++cc) Oacc[rf][cc] = zero;
  float lsum[4] = {0.f, 0.f, 0.f, 0.f};

#pragma unroll 1
  for (int bn = 0; bn < NBN; ++bn) {
    const int colbase = col0 + bn * 128;
    const bf16* xB = xnb + (size_t)colbase * D_;

    f32x4 Sacc[4][4];
#pragma unroll
    for (int rf = 0; rf < 4; ++rf)
#pragma unroll
      for (int cf = 0; cf < 4; ++cf) Sacc[rf][cf] = zero;

    // prologue (prev bn sealed by post-PV syncthreads; vm=0): stage(0)
    stage16(xA, A0, tid);
    stage16(xB, B0, tid);

#pragma unroll 1
    for (int kk = 0; kk < NKK; ++kk) {
      VM0;                           // own stage(kk) landed (only outstanding
                                     // VMEM: stage(kk+1) not yet issued)
      __builtin_amdgcn_s_barrier();  // bar1: all waves' stage(kk) landed;
                                     // also: all waves consumed reads(kk-1)
                                     // before arriving -> WAR-safe restage
      __builtin_amdgcn_sched_barrier(0);
      const char* Ac = (kk & 1) ? A1 : A0;
      const char* Bc = (kk & 1) ? B1 : B0;
      // swapped-S: Sacc = mfma(A=xn_frag, B=x_frag) -> lane holds
      // S[xn = wc*64+cf*16+g*4+r][xrow = wr*64+rf*16+c]
      {
        bf16x8 af[4], bv[4];
#pragma unroll
        for (int rf = 0; rf < 4; ++rf)
          af[rf] = *(const bf16x8*)(Ac + swz(wr * 64 + rf * 16 + c, g));
#pragma unroll
        for (int j = 0; j < 4; ++j)
          bv[j] = *(const bf16x8*)(Bc + swz(wc * 64 + j * 16 + c, g));
        if (kk < NKK - 1) {          // stage(kk+1): AFTER bar1 -> WAR-safe
          stage16(xA + (kk + 1) * 64, (kk & 1) ? A0 : A1, tid);
          stage16(xB + (kk + 1) * 64, (kk & 1) ? B0 : B1, tid);
        }
        __builtin_amdgcn_s_setprio(1);
#pragma unroll
        for (int j = 0; j < 4; ++j)
#pragma unroll
          for (int rf = 0; rf < 4; ++rf)
            Sacc[rf][j] = __builtin_amdgcn_mfma_f32_16x16x32_bf16(
                bv[j], af[rf], Sacc[rf][j], 0, 0, 0);
        __builtin_amdgcn_s_setprio(0);
      }
      {
        bf16x8 af[4], bv[4];
#pragma unroll
        for (int rf = 0; rf < 4; ++rf)
          af[rf] = *(const bf16x8*)(Ac + swz(wr * 64 + rf * 16 + c, 4 + g));
#pragma unroll
        for (int j = 0; j < 4; ++j)
          bv[j] = *(const bf16x8*)(Bc + swz(wc * 64 + j * 16 + c, 4 + g));
        __builtin_amdgcn_s_setprio(1);
#pragma unroll
        for (int j = 0; j < 4; ++j)
#pragma unroll
          for (int rf = 0; rf < 4; ++rf)
            Sacc[rf][j] = __builtin_amdgcn_mfma_f32_16x16x32_bf16(
                bv[j], af[rf], Sacc[rf][j], 0, 0, 0);
        __builtin_amdgcn_s_setprio(0);
      }
      // no bar2: next step's bar1 provides the WAR seal
    }
    __syncthreads();                 // seal kk15 readers; vm = 0 for alias reuse

    stageV(yT, colbase, Vb, tid);    // V -> B region (flies under exp)

    // exp: w = exp(-sqrt(max(xsq + xnsq - 2*dot, 0))); accumulate l
#pragma unroll
    for (int cf = 0; cf < 4; ++cf) {
      const float4 nsq4 = *(const float4*)(xnsq + colbase + wc * 64 + cf * 16 + g * 4);
#pragma unroll
      for (int rf = 0; rf < 4; ++rf)
#pragma unroll
        for (int r = 0; r < 4; ++r) {
          float d2 = xs[rf] + ((const float*)&nsq4)[r] - 2.0f * Sacc[rf][cf][r];
          d2 = fmaxf(d2, 0.0f);
          const float wv = __expf(-sqrtf(d2));
          lsum[rf] += wv;
          Sacc[rf][cf][r] = wv;
        }
    }

    // P-write -> A region [128 xrow][128 xn] swz2 (b64 per (rf,cf))
#pragma unroll
    for (int rf = 0; rf < 4; ++rf)
#pragma unroll
      for (int cf = 0; cf < 4; ++cf) {
        bf16x4 pk;
#pragma unroll
        for (int r = 0; r < 4; ++r) pk[r] = (bf16)Sacc[rf][cf][r];
        const int prow = wr * 64 + rf * 16 + c;
        const int gran = wc * 8 + cf * 2 + (g >> 1);
        *(bf16x4*)(Pb + (prow << 8) + ((gran ^ (prow & 15)) << 4) + (g & 1) * 8) = pk;
      }
    __syncthreads();                 // drains V (vmcnt0); P visible

    // PV: O[64 rows x 64 C-half] += P[64 x 128] @ V^T  (V [128C][128])
#pragma unroll
    for (int ks = 0; ks < 4; ++ks) {
      bf16x8 pa[4], vb[4];
#pragma unroll
      for (int rf = 0; rf < 4; ++rf)
        pa[rf] = *(const bf16x8*)(Pb + swz2(wr * 64 + rf * 16 + c, ks * 4 + g));
#pragma unroll
      for (int cc = 0; cc < 4; ++cc)
        vb[cc] = *(const bf16x8*)(Vb + swz2(wc * 64 + cc * 16 + c, ks * 4 + g));
      __builtin_amdgcn_s_setprio(1);
#pragma unroll
      for (int cc = 0; cc < 4; ++cc)
#pragma unroll
        for (int rf = 0; rf < 4; ++rf)
          Oacc[rf][cc] = __builtin_amdgcn_mfma_f32_16x16x32_bf16(pa[rf], vb[cc], Oacc[rf][cc], 0, 0, 0);
      __builtin_amdgcn_s_setprio(0);
    }
    __syncthreads();                 // seal P/V readers before next bn prologue
  }

  // ---- L reduce: over g (shfl), then the wc pair (LDS) ----
  float* Lr = (float*)Lds;           // [2 wc][128 rows]
#pragma unroll
  for (int rf = 0; rf < 4; ++rf) {
    float v = lsum[rf];
    v += __shfl_xor(v, 16);
    v += __shfl_xor(v, 32);
    if (g == 0) Lr[wc * 128 + wr * 64 + rf * 16 + c] = v;
  }
  __syncthreads();
  if (tid < 128)
    Lpart[(size_t)s * N_ + row0 + tid] = Lr[tid] + Lr[128 + tid];

  float* ob = Opart + ((size_t)s * N_ + row0) * C_;
#pragma unroll
  for (int rf = 0; rf < 4; ++rf)
#pragma unroll
    for (int cc = 0; cc < 4; ++cc)
#pragma unroll
      for (int r = 0; r < 4; ++r)
        ob[(wr * 64 + rf * 16 + g * 4 + r) * C_ + wc * 64 + cc * 16 + c] = Oacc[rf][cc][r];
}

// fused prep: rows [0,N) = x -> xb/xsq; rows [N, N+M) = xn -> xnb/xnsq
__global__ void prep_rows(const float* __restrict__ x, const float* __restrict__ xn,
                          bf16* __restrict__ xb, bf16* __restrict__ xnb,
                          float* __restrict__ xsq, float* __restrict__ xnsq)
{
  const int blk = blockIdx.x;
  const float* src; bf16* dst; float* sq; int row;
  if (blk < N_) { src = x;  dst = xb;  sq = xsq;  row = blk; }
  else          { src = xn; dst = xnb; sq = xnsq; row = blk - N_; }
  const int t = threadIdx.x;                   // 256 threads, 4 f32 each
  const float4 v = reinterpret_cast<const float4*>(src + (size_t)row * D_)[t];
  float ss = v.x * v.x + v.y * v.y + v.z * v.z + v.w * v.w;
  bf16x4 hv;
  hv[0] = (bf16)v.x; hv[1] = (bf16)v.y; hv[2] = (bf16)v.z; hv[3] = (bf16)v.w;
  *reinterpret_cast<bf16x4*>(dst + (size_t)row * D_ + t * 4) = hv;
#pragma unroll
  for (int o = 32; o > 0; o >>= 1) ss += __shfl_down(ss, o);
  __shared__ float red[4];
  if ((t & 63) == 0) red[t >> 6] = ss;
  __syncthreads();
  if (t == 0) sq[row] = red[0] + red[1] + red[2] + red[3];
}

// y[8192][128] f32 -> yT[128][8192] bf16
__global__ void prep_yT(const float* __restrict__ y, bf16* __restrict__ yT)
{
  __shared__ bf16 tile[C_][72];
  const int m0 = blockIdx.x * 64;
  const int t = threadIdx.x;
#pragma unroll
  for (int i = 0; i < 32; ++i) {
    const int idx = i * 256 + t;               // 0..8191
    const int ml = idx >> 7, cc = idx & 127;
    tile[cc][ml] = (bf16)y[(size_t)(m0 + ml) * C_ + cc];
  }
  __syncthreads();
#pragma unroll
  for (int i = 0; i < 32; ++i) {
    const int idx = i * 256 + t;
    const int cc = idx >> 6, ml = idx & 63;
    yT[(size_t)cc * M_ + m0 + ml] = tile[cc][ml];
  }
}

__global__ void combine(const float* __restrict__ Opart, const float* __restrict__ Lpart,
                        float* __restrict__ out)
{
  const int i = blockIdx.x * 256 + threadIdx.x;   // < N_*C_
  const int row = i >> 7;
  float o = 0.f, l = 0.f;
#pragma unroll
  for (int s = 0; s < SPLIT; ++s) {
    o += Opart[(size_t)s * N_ * C_ + i];
    l += Lpart[(size_t)s * N_ + row];
  }
  out[i] = o / l;
}

extern "C" void kernel_launch(void* const* d_in, const int* in_sizes, int n_in,
                              void* d_out, int out_size, void* d_ws, size_t ws_size,
                              hipStream_t stream)
{
  const float* x  = (const float*)d_in[0];
  const float* xn = (const float*)d_in[1];
  const float* y  = (const float*)d_in[2];
  // d_in[3] = log_T: computed-but-unused in the reference forward.
  float* out = (float*)d_out;

  char* ws = (char*)d_ws;
  bf16*  xb    = (bf16*)(ws);
  bf16*  xnb   = (bf16*)(ws + (size_t)8  * 1024 * 1024);
  bf16*  yT    = (bf16*)(ws + (size_t)24 * 1024 * 1024);
  float* xsq   = (float*)(ws + (size_t)26 * 1024 * 1024);
  float* xnsq  = (float*)(ws + (size_t)26 * 1024 * 1024 + 16 * 1024);
  float* Lpart = (float*)(ws + (size_t)26 * 1024 * 1024 + 64 * 1024);
  float* Opart = (float*)(ws + (size_t)27 * 1024 * 1024);   // 16 x 2 MiB

  prep_rows<<<N_ + M_, 256, 0, stream>>>(x, xn, xb, xnb, xsq, xnsq);
  prep_yT<<<M_ / 64, 256, 0, stream>>>(y, yT);
  nona_main<<<32 * SPLIT, 256, 0, stream>>>(xb, xnb, yT, xsq, xnsq, Opart, Lpart);
  combine<<<(N_ * C_) / 256, 256, 0, stream>>>(Opart, Lpart, out);
}